// Round 1
// baseline (2715.002 us; speedup 1.0000x reference)
//
#include <hip/hip_runtime.h>
#include <math.h>

#define B_ 2
#define N_ 2048
#define IN_DIM_ 256
#define DIM_ 256
#define H_ 8
#define DH_ 32
#define TOPK_ 4
#define EPS_ 1e-5f
#define TEMP_ 0.17677669529663687f  // 1/sqrt(32)

// ---------------- LayerNorm: one row (256 floats) per 64-lane wave ----------------
__global__ __launch_bounds__(256) void ln_kernel(const float* __restrict__ x,
                                                 const float* __restrict__ gamma,
                                                 const float* __restrict__ beta,
                                                 float* __restrict__ xn) {
  int w = threadIdx.x >> 6, ld = threadIdx.x & 63;
  int row = blockIdx.x * 4 + w;
  const float4* xr = (const float4*)(x + (size_t)row * 256);
  float4 v = xr[ld];
  float s = v.x + v.y + v.z + v.w;
  float ss = v.x * v.x + v.y * v.y + v.z * v.z + v.w * v.w;
  #pragma unroll
  for (int off = 1; off < 64; off <<= 1) {
    s += __shfl_xor(s, off);
    ss += __shfl_xor(ss, off);
  }
  float mu = s * (1.0f / 256.0f);
  float var = ss * (1.0f / 256.0f) - mu * mu;
  float rstd = rsqrtf(var + EPS_);
  float4 g = ((const float4*)gamma)[ld];
  float4 bt = ((const float4*)beta)[ld];
  float4 o;
  o.x = (v.x - mu) * rstd * g.x + bt.x;
  o.y = (v.y - mu) * rstd * g.y + bt.y;
  o.z = (v.z - mu) * rstd * g.z + bt.z;
  o.w = (v.w - mu) * rstd * g.w + bt.w;
  ((float4*)(xn + (size_t)row * 256))[ld] = o;
}

// ---------------- fp32 tiled GEMM: C[m][n] = sum_k A[m*K+k] * Bm[n*K+k] ----------------
template <bool PROJ>
__global__ __launch_bounds__(256) void gemm_nt(const float* __restrict__ A,
                                               const float* __restrict__ Bm,
                                               float* __restrict__ C,
                                               const float* __restrict__ vres,
                                               const float* __restrict__ bias,
                                               int K, int ldc) {
  __shared__ float As[32][64];
  __shared__ float Bs[32][64];
  int m0 = blockIdx.x * 64, n0 = blockIdx.y * 64;
  int t = threadIdx.x;
  int tm = t & 15, tn = t >> 4;
  float acc[4][4] = {};
  for (int k0 = 0; k0 < K; k0 += 32) {
    __syncthreads();
    for (int f = t; f < 512; f += 256) {
      int row = f >> 3, j = f & 7;
      float4 a = *(const float4*)(A + (size_t)(m0 + row) * K + k0 + j * 4);
      As[j * 4 + 0][row] = a.x; As[j * 4 + 1][row] = a.y;
      As[j * 4 + 2][row] = a.z; As[j * 4 + 3][row] = a.w;
      float4 b = *(const float4*)(Bm + (size_t)(n0 + row) * K + k0 + j * 4);
      Bs[j * 4 + 0][row] = b.x; Bs[j * 4 + 1][row] = b.y;
      Bs[j * 4 + 2][row] = b.z; Bs[j * 4 + 3][row] = b.w;
    }
    __syncthreads();
    #pragma unroll
    for (int k = 0; k < 32; k++) {
      float4 a = *(const float4*)&As[k][tm * 4];
      float4 b = *(const float4*)&Bs[k][tn * 4];
      float av[4] = {a.x, a.y, a.z, a.w};
      float bv[4] = {b.x, b.y, b.z, b.w};
      #pragma unroll
      for (int i = 0; i < 4; i++)
        #pragma unroll
        for (int j = 0; j < 4; j++)
          acc[i][j] = fmaf(av[i], bv[j], acc[i][j]);
    }
  }
  #pragma unroll
  for (int i = 0; i < 4; i++) {
    int m = m0 + tm * 4 + i;
    int n = n0 + tn * 4;
    float4 r = {acc[i][0], acc[i][1], acc[i][2], acc[i][3]};
    if (PROJ) {
      float4 vr = *(const float4*)(vres + (size_t)m * 768 + n);
      float4 bb = *(const float4*)(bias + n);
      r.x += vr.x + bb.x; r.y += vr.y + bb.y;
      r.z += vr.z + bb.z; r.w += vr.w + bb.w;
    }
    *(float4*)(C + (size_t)m * ldc + n) = r;
  }
}

// ---------------- Flash attention v2: lane=row, waves partition columns ----------------
// Block: 512 threads (8 waves) handles 64 query rows for one (b,h).
// Wave w owns s-columns w*8..w*8+7 of each 64-wide KV tile; lane (0..63) = query row.
// K[col]/V[col] are wave-uniform -> LDS broadcast reads; softmax + top-4 fully per-lane.
// Per-wave partial (m,l,o,top4) merged across the 8 column-slices at the end via LDS.

__device__ __forceinline__ void stage16(const float* g, float* l) {
  __builtin_amdgcn_global_load_lds(
      (const __attribute__((address_space(1))) unsigned int*)g,
      (__attribute__((address_space(3))) unsigned int*)l, 16, 0, 0);
}

__global__ __launch_bounds__(512, 4) void attn_kernel(const float* __restrict__ qkv,
                                                      float* __restrict__ msg,
                                                      float* __restrict__ out_s,
                                                      float* __restrict__ out_i) {
  const int l0 = blockIdx.x * 64;
  const int h = blockIdx.y;
  const int b = blockIdx.z;
  const int t = threadIdx.x;
  const int wid = t >> 6;
  const int lane = t & 63;
  const int c0 = wid * 8;  // this wave's column offset within a tile

  __shared__ float Ks[2][64][32];
  __shared__ float Vs[2][64][32];
  __shared__ float Pm[8][64];
  __shared__ float Pl[8][64];
  __shared__ float Ptv[8][64][5];
  __shared__ int   Pti[8][64][5];
  __shared__ float AccO[64][33];  // padded: atomics conflict-free across lanes
  __shared__ float Fsc[64][4];
  __shared__ int   Ffi[64][4];
  __shared__ float Flinv[64];

  // ---- load this lane's q row (temp-scaled) ----
  const float* qrow = qkv + ((size_t)(b * N_) + l0 + lane) * 768 + h * DH_;
  float4 q[8];
  #pragma unroll
  for (int j = 0; j < 8; j++) {
    float4 v = ((const float4*)qrow)[j];
    v.x *= TEMP_; v.y *= TEMP_; v.z *= TEMP_; v.w *= TEMP_;
    q[j] = v;
  }

  float4 o[8];
  #pragma unroll
  for (int j = 0; j < 8; j++) o[j] = make_float4(0.f, 0.f, 0.f, 0.f);
  float m = -INFINITY, l = 0.f;
  float tv[4];
  int ti[4];
  #pragma unroll
  for (int i = 0; i < 4; i++) { tv[i] = -INFINITY; ti[i] = 0x7fffffff; }

  // ---- staging setup: thread t loads flat 16B element t of the K tile (and V tile) ----
  const int scol = t >> 3, sch = t & 7;
  const float* gK0 = qkv + (size_t)(b * N_) * 768 + 256 + h * DH_ +
                     (size_t)scol * 768 + sch * 4;
  float* lK0 = &Ks[0][0][0] + (size_t)wid * 256;  // wave-uniform LDS base (lane*16B auto)
  float* lV0 = &Vs[0][0][0] + (size_t)wid * 256;

#define STAGE(bb, s0)                                          \
  do {                                                         \
    const float* gk_ = gK0 + (size_t)(s0) * 768;               \
    stage16(gk_, lK0 + (bb) * 2048);                           \
    stage16(gk_ + 256, lV0 + (bb) * 2048);                     \
  } while (0)

  STAGE(0, 0);
  asm volatile("s_waitcnt vmcnt(0)" ::: "memory");
  __syncthreads();

  for (int t0 = 0; t0 < N_ / 64; ++t0) {
    const int cur = t0 & 1;
    const int s0 = t0 * 64;
    if (t0 + 1 < N_ / 64) STAGE(cur ^ 1, s0 + 64);  // prefetch hides under compute

    const float (*Kb)[32] = Ks[cur];
    const float (*Vb)[32] = Vs[cur];

    // ---- QK: 8 columns, uniform broadcast reads, interleaved FMA chains ----
    float sv[8];
    #pragma unroll
    for (int g2 = 0; g2 < 2; ++g2) {
      float a0 = 0.f, a1 = 0.f, a2 = 0.f, a3 = 0.f;
      const int cb = c0 + g2 * 4;
      #pragma unroll
      for (int ch = 0; ch < 8; ++ch) {
        float4 qv = q[ch];
        float4 k0 = *(const float4*)&Kb[cb + 0][ch * 4];
        float4 k1 = *(const float4*)&Kb[cb + 1][ch * 4];
        float4 k2 = *(const float4*)&Kb[cb + 2][ch * 4];
        float4 k3 = *(const float4*)&Kb[cb + 3][ch * 4];
        a0 = fmaf(qv.x, k0.x, a0); a1 = fmaf(qv.x, k1.x, a1);
        a2 = fmaf(qv.x, k2.x, a2); a3 = fmaf(qv.x, k3.x, a3);
        a0 = fmaf(qv.y, k0.y, a0); a1 = fmaf(qv.y, k1.y, a1);
        a2 = fmaf(qv.y, k2.y, a2); a3 = fmaf(qv.y, k3.y, a3);
        a0 = fmaf(qv.z, k0.z, a0); a1 = fmaf(qv.z, k1.z, a1);
        a2 = fmaf(qv.z, k2.z, a2); a3 = fmaf(qv.z, k3.z, a3);
        a0 = fmaf(qv.w, k0.w, a0); a1 = fmaf(qv.w, k1.w, a1);
        a2 = fmaf(qv.w, k2.w, a2); a3 = fmaf(qv.w, k3.w, a3);
      }
      sv[g2 * 4 + 0] = a0; sv[g2 * 4 + 1] = a1;
      sv[g2 * 4 + 2] = a2; sv[g2 * 4 + 3] = a3;
    }

    // ---- top-4 update (raw logits, compile-time-indexed cascade: no scratch) ----
    #pragma unroll
    for (int i = 0; i < 8; ++i) {
      float sval = sv[i];
      int idx = s0 + c0 + i;
      if (sval > tv[3] || (sval == tv[3] && idx < ti[3])) {
        bool i2 = (sval > tv[2]) || (sval == tv[2] && idx < ti[2]);
        bool i1 = (sval > tv[1]) || (sval == tv[1] && idx < ti[1]);
        bool i0 = (sval > tv[0]) || (sval == tv[0] && idx < ti[0]);
        tv[3] = i2 ? tv[2] : sval; ti[3] = i2 ? ti[2] : idx;
        float nv2 = i1 ? tv[1] : sval; int ni2 = i1 ? ti[1] : idx;
        float nv1 = i0 ? tv[0] : sval; int ni1 = i0 ? ti[0] : idx;
        if (i2) { tv[2] = nv2; ti[2] = ni2; }
        if (i1) { tv[1] = nv1; ti[1] = ni1; }
        if (i0) { tv[0] = sval; ti[0] = idx; }
      }
    }

    // ---- online softmax (fully per-lane) ----
    float tmax = fmaxf(fmaxf(fmaxf(sv[0], sv[1]), fmaxf(sv[2], sv[3])),
                       fmaxf(fmaxf(sv[4], sv[5]), fmaxf(sv[6], sv[7])));
    float mnew = fmaxf(m, tmax);
    float alpha = __expf(m - mnew);
    float p[8];
    float ps = 0.f;
    #pragma unroll
    for (int i = 0; i < 8; ++i) { p[i] = __expf(sv[i] - mnew); ps += p[i]; }
    l = l * alpha + ps;
    m = mnew;
    #pragma unroll
    for (int ch = 0; ch < 8; ++ch) {
      o[ch].x *= alpha; o[ch].y *= alpha; o[ch].z *= alpha; o[ch].w *= alpha;
    }

    // ---- PV: 8 columns x 32 dims, uniform broadcast V, 32 independent acc chains ----
    #pragma unroll
    for (int i = 0; i < 8; ++i) {
      float pi = p[i];
      const float* vcol = &Vb[c0 + i][0];
      #pragma unroll
      for (int ch = 0; ch < 8; ++ch) {
        float4 vv = *(const float4*)(vcol + ch * 4);
        o[ch].x = fmaf(pi, vv.x, o[ch].x);
        o[ch].y = fmaf(pi, vv.y, o[ch].y);
        o[ch].z = fmaf(pi, vv.z, o[ch].z);
        o[ch].w = fmaf(pi, vv.w, o[ch].w);
      }
    }

    __syncthreads();  // compiler drains vmcnt here: prefetch already landed under compute
  }
#undef STAGE

  // ---- merge the 8 per-wave column-slice partials ----
  Pm[wid][lane] = m;
  Pl[wid][lane] = l;
  #pragma unroll
  for (int i = 0; i < 4; ++i) { Ptv[wid][lane][i] = tv[i]; Pti[wid][lane][i] = ti[i]; }
  for (int i = t; i < 64 * 33; i += 512) (&AccO[0][0])[i] = 0.f;
  __syncthreads();

  float mg = Pm[0][lane];
  #pragma unroll
  for (int j = 1; j < 8; ++j) mg = fmaxf(mg, Pm[j][lane]);
  float lg = 0.f;
  #pragma unroll
  for (int j = 0; j < 8; ++j) lg += Pl[j][lane] * __expf(Pm[j][lane] - mg);
  float aw = __expf(m - mg);
  #pragma unroll
  for (int ch = 0; ch < 8; ++ch) {
    atomicAdd(&AccO[lane][ch * 4 + 0], o[ch].x * aw);
    atomicAdd(&AccO[lane][ch * 4 + 1], o[ch].y * aw);
    atomicAdd(&AccO[lane][ch * 4 + 2], o[ch].z * aw);
    atomicAdd(&AccO[lane][ch * 4 + 3], o[ch].w * aw);
  }
  __syncthreads();

  if (wid == 0) {
    float linv = 1.f / lg;
    Flinv[lane] = linv;
    float fv[4];
    int fi[4];
    #pragma unroll
    for (int r = 0; r < 4; ++r) {
      float best = -INFINITY;
      int bi = 0x7fffffff, bj = 0, bii = 0;
      #pragma unroll
      for (int j = 0; j < 8; ++j)
        #pragma unroll
        for (int i2 = 0; i2 < 4; ++i2) {
          float v2 = Ptv[j][lane][i2];
          int ix = Pti[j][lane][i2];
          if (v2 > best || (v2 == best && ix < bi)) { best = v2; bi = ix; bj = j; bii = i2; }
        }
      Ptv[bj][lane][bii] = -INFINITY;  // LDS-indexed mark, stays off scratch
      fv[r] = best;
      fi[r] = bi;
    }
    size_t base = ((size_t)(b * N_) + l0 + lane) * TOPK_;
    #pragma unroll
    for (int r = 0; r < 4; ++r) {
      float sc = __expf(fv[r] - mg) * linv;
      Fsc[lane][r] = sc;
      Ffi[lane][r] = fi[r];
      out_s[(base + r) * H_ + h] = sc;
      out_i[(base + r) * H_ + h] = (float)fi[r];
    }
  }
  __syncthreads();

  // ---- final: normalize, subtract top-4 contributions, coalesced write ----
  {
    int r = t >> 3, dc = t & 7;
    float linv = Flinv[r];
    float ax = AccO[r][dc * 4 + 0] * linv;
    float ay = AccO[r][dc * 4 + 1] * linv;
    float az = AccO[r][dc * 4 + 2] * linv;
    float aw2 = AccO[r][dc * 4 + 3] * linv;
    #pragma unroll
    for (int k = 0; k < 4; ++k) {
      int idx = Ffi[r][k];
      float sc = Fsc[r][k];
      const float* vp = qkv + ((size_t)(b * N_) + idx) * 768 + 512 + h * DH_ + dc * 4;
      float4 vv = *(const float4*)vp;
      ax = fmaf(-sc, vv.x, ax); ay = fmaf(-sc, vv.y, ay);
      az = fmaf(-sc, vv.z, az); aw2 = fmaf(-sc, vv.w, aw2);
    }
    float4 r4 = {ax, ay, az, aw2};
    *(float4*)(msg + ((size_t)(b * N_) + l0 + r) * DIM_ + h * DH_ + dc * 4) = r4;
  }
}

extern "C" void kernel_launch(void* const* d_in, const int* in_sizes, int n_in,
                              void* d_out, int out_size, void* d_ws, size_t ws_size,
                              hipStream_t stream) {
  const float* points = (const float*)d_in[0];
  const float* norm_gamma = (const float*)d_in[1];
  const float* norm_beta = (const float*)d_in[2];
  const float* w_qkv = (const float*)d_in[3];
  const float* w_proj = (const float*)d_in[4];
  const float* b_proj = (const float*)d_in[5];

  float* out0 = (float*)d_out;                       // message_flat (4096*256)
  float* out1 = out0 + (size_t)4096 * 256;           // topk_score (4096*4*8)
  float* out2 = out1 + (size_t)4096 * 4 * 8;         // topk_idx as float

  float* xn = (float*)d_ws;                          // 4096*256
  float* qkv = xn + (size_t)4096 * 256;              // 4096*768
  float* msg = qkv + (size_t)4096 * 768;             // 4096*256

  ln_kernel<<<1024, 256, 0, stream>>>(points, norm_gamma, norm_beta, xn);
  gemm_nt<false><<<dim3(64, 12), 256, 0, stream>>>(xn, w_qkv, qkv, nullptr,
                                                   nullptr, 256, 768);
  attn_kernel<<<dim3(N_ / 64, H_, B_), 512, 0, stream>>>(qkv, msg, out1, out2);
  gemm_nt<true><<<dim3(64, 4), 256, 0, stream>>>(msg, w_proj, out0, qkv + 512,
                                                 b_proj, 256, 256);
}

// Round 2
// 957.985 us; speedup vs baseline: 2.8341x; 2.8341x over previous
//
#include <hip/hip_runtime.h>
#include <math.h>

#define B_ 2
#define N_ 2048
#define IN_DIM_ 256
#define DIM_ 256
#define H_ 8
#define DH_ 32
#define TOPK_ 4
#define EPS_ 1e-5f
#define TEMP_ 0.17677669529663687f  // 1/sqrt(32)

// ---------------- LayerNorm: one row (256 floats) per 64-lane wave ----------------
__global__ __launch_bounds__(256) void ln_kernel(const float* __restrict__ x,
                                                 const float* __restrict__ gamma,
                                                 const float* __restrict__ beta,
                                                 float* __restrict__ xn) {
  int w = threadIdx.x >> 6, ld = threadIdx.x & 63;
  int row = blockIdx.x * 4 + w;
  const float4* xr = (const float4*)(x + (size_t)row * 256);
  float4 v = xr[ld];
  float s = v.x + v.y + v.z + v.w;
  float ss = v.x * v.x + v.y * v.y + v.z * v.z + v.w * v.w;
  #pragma unroll
  for (int off = 1; off < 64; off <<= 1) {
    s += __shfl_xor(s, off);
    ss += __shfl_xor(ss, off);
  }
  float mu = s * (1.0f / 256.0f);
  float var = ss * (1.0f / 256.0f) - mu * mu;
  float rstd = rsqrtf(var + EPS_);
  float4 g = ((const float4*)gamma)[ld];
  float4 bt = ((const float4*)beta)[ld];
  float4 o;
  o.x = (v.x - mu) * rstd * g.x + bt.x;
  o.y = (v.y - mu) * rstd * g.y + bt.y;
  o.z = (v.z - mu) * rstd * g.z + bt.z;
  o.w = (v.w - mu) * rstd * g.w + bt.w;
  ((float4*)(xn + (size_t)row * 256))[ld] = o;
}

// ---------------- fp32 tiled GEMM: C[m][n] = sum_k A[m*K+k] * Bm[n*K+k] ----------------
template <bool PROJ>
__global__ __launch_bounds__(256) void gemm_nt(const float* __restrict__ A,
                                               const float* __restrict__ Bm,
                                               float* __restrict__ C,
                                               const float* __restrict__ vres,
                                               const float* __restrict__ bias,
                                               int K, int ldc) {
  __shared__ float As[32][64];
  __shared__ float Bs[32][64];
  int m0 = blockIdx.x * 64, n0 = blockIdx.y * 64;
  int t = threadIdx.x;
  int tm = t & 15, tn = t >> 4;
  float acc[4][4] = {};
  for (int k0 = 0; k0 < K; k0 += 32) {
    __syncthreads();
    for (int f = t; f < 512; f += 256) {
      int row = f >> 3, j = f & 7;
      float4 a = *(const float4*)(A + (size_t)(m0 + row) * K + k0 + j * 4);
      As[j * 4 + 0][row] = a.x; As[j * 4 + 1][row] = a.y;
      As[j * 4 + 2][row] = a.z; As[j * 4 + 3][row] = a.w;
      float4 b = *(const float4*)(Bm + (size_t)(n0 + row) * K + k0 + j * 4);
      Bs[j * 4 + 0][row] = b.x; Bs[j * 4 + 1][row] = b.y;
      Bs[j * 4 + 2][row] = b.z; Bs[j * 4 + 3][row] = b.w;
    }
    __syncthreads();
    #pragma unroll
    for (int k = 0; k < 32; k++) {
      float4 a = *(const float4*)&As[k][tm * 4];
      float4 b = *(const float4*)&Bs[k][tn * 4];
      float av[4] = {a.x, a.y, a.z, a.w};
      float bv[4] = {b.x, b.y, b.z, b.w};
      #pragma unroll
      for (int i = 0; i < 4; i++)
        #pragma unroll
        for (int j = 0; j < 4; j++)
          acc[i][j] = fmaf(av[i], bv[j], acc[i][j]);
    }
  }
  #pragma unroll
  for (int i = 0; i < 4; i++) {
    int m = m0 + tm * 4 + i;
    int n = n0 + tn * 4;
    float4 r = {acc[i][0], acc[i][1], acc[i][2], acc[i][3]};
    if (PROJ) {
      float4 vr = *(const float4*)(vres + (size_t)m * 768 + n);
      float4 bb = *(const float4*)(bias + n);
      r.x += vr.x + bb.x; r.y += vr.y + bb.y;
      r.z += vr.z + bb.z; r.w += vr.w + bb.w;
    }
    *(float4*)(C + (size_t)m * ldc + n) = r;
  }
}

// ---------------- Flash attention v2: lane=row, waves partition columns ----------------
// Block: 512 threads (8 waves) handles 64 query rows for one (b,h).
// Wave w owns s-columns w*8..w*8+7 of each 64-wide KV tile; lane (0..63) = query row.
// K[col]/V[col] are wave-uniform -> LDS broadcast reads; softmax + top-4 fully per-lane.
// __launch_bounds__(512, 2): min 2 blocks/CU -> 128-VGPR cap (4 waves/SIMD, no spill).
// NOTE: (512, 4) capped VGPRs at 64 and spilled q[]/o[] to scratch (9 GB HBM traffic).

__device__ __forceinline__ void stage16(const float* g, float* l) {
  __builtin_amdgcn_global_load_lds(
      (const __attribute__((address_space(1))) unsigned int*)g,
      (__attribute__((address_space(3))) unsigned int*)l, 16, 0, 0);
}

__global__ __launch_bounds__(512, 2) void attn_kernel(const float* __restrict__ qkv,
                                                      float* __restrict__ msg,
                                                      float* __restrict__ out_s,
                                                      float* __restrict__ out_i) {
  const int l0 = blockIdx.x * 64;
  const int h = blockIdx.y;
  const int b = blockIdx.z;
  const int t = threadIdx.x;
  const int wid = t >> 6;
  const int lane = t & 63;
  const int c0 = wid * 8;  // this wave's column offset within a tile

  __shared__ float Ks[2][64][32];
  __shared__ float Vs[2][64][32];
  __shared__ float Pm[8][64];
  __shared__ float Pl[8][64];
  __shared__ float Ptv[8][64][5];
  __shared__ int   Pti[8][64][5];
  __shared__ float AccO[64][33];  // padded: atomics conflict-free across lanes
  __shared__ float Fsc[64][4];
  __shared__ int   Ffi[64][4];
  __shared__ float Flinv[64];

  // ---- load this lane's q row (temp-scaled) ----
  const float* qrow = qkv + ((size_t)(b * N_) + l0 + lane) * 768 + h * DH_;
  float4 q[8];
  #pragma unroll
  for (int j = 0; j < 8; j++) {
    float4 v = ((const float4*)qrow)[j];
    v.x *= TEMP_; v.y *= TEMP_; v.z *= TEMP_; v.w *= TEMP_;
    q[j] = v;
  }

  float4 o[8];
  #pragma unroll
  for (int j = 0; j < 8; j++) o[j] = make_float4(0.f, 0.f, 0.f, 0.f);
  float m = -INFINITY, l = 0.f;
  float tv[4];
  int ti[4];
  #pragma unroll
  for (int i = 0; i < 4; i++) { tv[i] = -INFINITY; ti[i] = 0x7fffffff; }

  // ---- staging setup: thread t loads flat 16B element t of the K tile (and V tile) ----
  const int scol = t >> 3, sch = t & 7;
  const float* gK0 = qkv + (size_t)(b * N_) * 768 + 256 + h * DH_ +
                     (size_t)scol * 768 + sch * 4;
  float* lK0 = &Ks[0][0][0] + (size_t)wid * 256;  // wave-uniform LDS base (lane*16B auto)
  float* lV0 = &Vs[0][0][0] + (size_t)wid * 256;

#define STAGE(bb, s0)                                          \
  do {                                                         \
    const float* gk_ = gK0 + (size_t)(s0) * 768;               \
    stage16(gk_, lK0 + (bb) * 2048);                           \
    stage16(gk_ + 256, lV0 + (bb) * 2048);                     \
  } while (0)

  STAGE(0, 0);
  asm volatile("s_waitcnt vmcnt(0)" ::: "memory");
  __syncthreads();

  for (int t0 = 0; t0 < N_ / 64; ++t0) {
    const int cur = t0 & 1;
    const int s0 = t0 * 64;
    if (t0 + 1 < N_ / 64) STAGE(cur ^ 1, s0 + 64);  // prefetch hides under compute

    const float (*Kb)[32] = Ks[cur];
    const float (*Vb)[32] = Vs[cur];

    // ---- QK: 8 columns, uniform broadcast reads, interleaved FMA chains ----
    float sv[8];
    #pragma unroll
    for (int g2 = 0; g2 < 2; ++g2) {
      float a0 = 0.f, a1 = 0.f, a2 = 0.f, a3 = 0.f;
      const int cb = c0 + g2 * 4;
      #pragma unroll
      for (int ch = 0; ch < 8; ++ch) {
        float4 qv = q[ch];
        float4 k0 = *(const float4*)&Kb[cb + 0][ch * 4];
        float4 k1 = *(const float4*)&Kb[cb + 1][ch * 4];
        float4 k2 = *(const float4*)&Kb[cb + 2][ch * 4];
        float4 k3 = *(const float4*)&Kb[cb + 3][ch * 4];
        a0 = fmaf(qv.x, k0.x, a0); a1 = fmaf(qv.x, k1.x, a1);
        a2 = fmaf(qv.x, k2.x, a2); a3 = fmaf(qv.x, k3.x, a3);
        a0 = fmaf(qv.y, k0.y, a0); a1 = fmaf(qv.y, k1.y, a1);
        a2 = fmaf(qv.y, k2.y, a2); a3 = fmaf(qv.y, k3.y, a3);
        a0 = fmaf(qv.z, k0.z, a0); a1 = fmaf(qv.z, k1.z, a1);
        a2 = fmaf(qv.z, k2.z, a2); a3 = fmaf(qv.z, k3.z, a3);
        a0 = fmaf(qv.w, k0.w, a0); a1 = fmaf(qv.w, k1.w, a1);
        a2 = fmaf(qv.w, k2.w, a2); a3 = fmaf(qv.w, k3.w, a3);
      }
      sv[g2 * 4 + 0] = a0; sv[g2 * 4 + 1] = a1;
      sv[g2 * 4 + 2] = a2; sv[g2 * 4 + 3] = a3;
    }

    // ---- top-4 update (raw logits, compile-time-indexed cascade: no scratch) ----
    #pragma unroll
    for (int i = 0; i < 8; ++i) {
      float sval = sv[i];
      int idx = s0 + c0 + i;
      if (sval > tv[3] || (sval == tv[3] && idx < ti[3])) {
        bool i2 = (sval > tv[2]) || (sval == tv[2] && idx < ti[2]);
        bool i1 = (sval > tv[1]) || (sval == tv[1] && idx < ti[1]);
        bool i0 = (sval > tv[0]) || (sval == tv[0] && idx < ti[0]);
        tv[3] = i2 ? tv[2] : sval; ti[3] = i2 ? ti[2] : idx;
        float nv2 = i1 ? tv[1] : sval; int ni2 = i1 ? ti[1] : idx;
        float nv1 = i0 ? tv[0] : sval; int ni1 = i0 ? ti[0] : idx;
        if (i2) { tv[2] = nv2; ti[2] = ni2; }
        if (i1) { tv[1] = nv1; ti[1] = ni1; }
        if (i0) { tv[0] = sval; ti[0] = idx; }
      }
    }

    // ---- online softmax (fully per-lane); p[] overwrites sv[] in place ----
    float tmax = fmaxf(fmaxf(fmaxf(sv[0], sv[1]), fmaxf(sv[2], sv[3])),
                       fmaxf(fmaxf(sv[4], sv[5]), fmaxf(sv[6], sv[7])));
    float mnew = fmaxf(m, tmax);
    float alpha = __expf(m - mnew);
    float ps = 0.f;
    #pragma unroll
    for (int i = 0; i < 8; ++i) { sv[i] = __expf(sv[i] - mnew); ps += sv[i]; }
    l = l * alpha + ps;
    m = mnew;
    #pragma unroll
    for (int ch = 0; ch < 8; ++ch) {
      o[ch].x *= alpha; o[ch].y *= alpha; o[ch].z *= alpha; o[ch].w *= alpha;
    }

    // ---- PV: 8 columns x 32 dims, uniform broadcast V, 32 independent acc chains ----
    #pragma unroll
    for (int i = 0; i < 8; ++i) {
      float pi = sv[i];
      const float* vcol = &Vb[c0 + i][0];
      #pragma unroll
      for (int ch = 0; ch < 8; ++ch) {
        float4 vv = *(const float4*)(vcol + ch * 4);
        o[ch].x = fmaf(pi, vv.x, o[ch].x);
        o[ch].y = fmaf(pi, vv.y, o[ch].y);
        o[ch].z = fmaf(pi, vv.z, o[ch].z);
        o[ch].w = fmaf(pi, vv.w, o[ch].w);
      }
    }

    __syncthreads();  // compiler drains vmcnt here: prefetch already landed under compute
  }
#undef STAGE

  // ---- merge the 8 per-wave column-slice partials ----
  Pm[wid][lane] = m;
  Pl[wid][lane] = l;
  #pragma unroll
  for (int i = 0; i < 4; ++i) { Ptv[wid][lane][i] = tv[i]; Pti[wid][lane][i] = ti[i]; }
  for (int i = t; i < 64 * 33; i += 512) (&AccO[0][0])[i] = 0.f;
  __syncthreads();

  float mg = Pm[0][lane];
  #pragma unroll
  for (int j = 1; j < 8; ++j) mg = fmaxf(mg, Pm[j][lane]);
  float lg = 0.f;
  #pragma unroll
  for (int j = 0; j < 8; ++j) lg += Pl[j][lane] * __expf(Pm[j][lane] - mg);
  float aw = __expf(m - mg);
  #pragma unroll
  for (int ch = 0; ch < 8; ++ch) {
    atomicAdd(&AccO[lane][ch * 4 + 0], o[ch].x * aw);
    atomicAdd(&AccO[lane][ch * 4 + 1], o[ch].y * aw);
    atomicAdd(&AccO[lane][ch * 4 + 2], o[ch].z * aw);
    atomicAdd(&AccO[lane][ch * 4 + 3], o[ch].w * aw);
  }
  __syncthreads();

  if (wid == 0) {
    float linv = 1.f / lg;
    Flinv[lane] = linv;
    float fv[4];
    int fi[4];
    #pragma unroll
    for (int r = 0; r < 4; ++r) {
      float best = -INFINITY;
      int bi = 0x7fffffff, bj = 0, bii = 0;
      #pragma unroll
      for (int j = 0; j < 8; ++j)
        #pragma unroll
        for (int i2 = 0; i2 < 4; ++i2) {
          float v2 = Ptv[j][lane][i2];
          int ix = Pti[j][lane][i2];
          if (v2 > best || (v2 == best && ix < bi)) { best = v2; bi = ix; bj = j; bii = i2; }
        }
      Ptv[bj][lane][bii] = -INFINITY;  // LDS-indexed mark, stays off scratch
      fv[r] = best;
      fi[r] = bi;
    }
    size_t base = ((size_t)(b * N_) + l0 + lane) * TOPK_;
    #pragma unroll
    for (int r = 0; r < 4; ++r) {
      float sc = __expf(fv[r] - mg) * linv;
      Fsc[lane][r] = sc;
      Ffi[lane][r] = fi[r];
      out_s[(base + r) * H_ + h] = sc;
      out_i[(base + r) * H_ + h] = (float)fi[r];
    }
  }
  __syncthreads();

  // ---- final: normalize, subtract top-4 contributions, coalesced write ----
  {
    int r = t >> 3, dc = t & 7;
    float linv = Flinv[r];
    float ax = AccO[r][dc * 4 + 0] * linv;
    float ay = AccO[r][dc * 4 + 1] * linv;
    float az = AccO[r][dc * 4 + 2] * linv;
    float aw2 = AccO[r][dc * 4 + 3] * linv;
    #pragma unroll
    for (int k = 0; k < 4; ++k) {
      int idx = Ffi[r][k];
      float sc = Fsc[r][k];
      const float* vp = qkv + ((size_t)(b * N_) + idx) * 768 + 512 + h * DH_ + dc * 4;
      float4 vv = *(const float4*)vp;
      ax = fmaf(-sc, vv.x, ax); ay = fmaf(-sc, vv.y, ay);
      az = fmaf(-sc, vv.z, az); aw2 = fmaf(-sc, vv.w, aw2);
    }
    float4 r4 = {ax, ay, az, aw2};
    *(float4*)(msg + ((size_t)(b * N_) + l0 + r) * DIM_ + h * DH_ + dc * 4) = r4;
  }
}

extern "C" void kernel_launch(void* const* d_in, const int* in_sizes, int n_in,
                              void* d_out, int out_size, void* d_ws, size_t ws_size,
                              hipStream_t stream) {
  const float* points = (const float*)d_in[0];
  const float* norm_gamma = (const float*)d_in[1];
  const float* norm_beta = (const float*)d_in[2];
  const float* w_qkv = (const float*)d_in[3];
  const float* w_proj = (const float*)d_in[4];
  const float* b_proj = (const float*)d_in[5];

  float* out0 = (float*)d_out;                       // message_flat (4096*256)
  float* out1 = out0 + (size_t)4096 * 256;           // topk_score (4096*4*8)
  float* out2 = out1 + (size_t)4096 * 4 * 8;         // topk_idx as float

  float* xn = (float*)d_ws;                          // 4096*256
  float* qkv = xn + (size_t)4096 * 256;              // 4096*768
  float* msg = qkv + (size_t)4096 * 768;             // 4096*256

  ln_kernel<<<1024, 256, 0, stream>>>(points, norm_gamma, norm_beta, xn);
  gemm_nt<false><<<dim3(64, 12), 256, 0, stream>>>(xn, w_qkv, qkv, nullptr,
                                                   nullptr, 256, 768);
  attn_kernel<<<dim3(N_ / 64, H_, B_), 512, 0, stream>>>(qkv, msg, out1, out2);
  gemm_nt<true><<<dim3(64, 4), 256, 0, stream>>>(msg, w_proj, out0, qkv + 512,
                                                 b_proj, 256, 256);
}

// Round 3
// 444.920 us; speedup vs baseline: 6.1022x; 2.1532x over previous
//
#include <hip/hip_runtime.h>
#include <math.h>

#define B_ 2
#define N_ 2048
#define IN_DIM_ 256
#define DIM_ 256
#define H_ 8
#define DH_ 32
#define TOPK_ 4
#define EPS_ 1e-5f
#define TEMP_ 0.17677669529663687f  // 1/sqrt(32)

// ---------------- LayerNorm: one row (256 floats) per 64-lane wave ----------------
__global__ __launch_bounds__(256) void ln_kernel(const float* __restrict__ x,
                                                 const float* __restrict__ gamma,
                                                 const float* __restrict__ beta,
                                                 float* __restrict__ xn) {
  int w = threadIdx.x >> 6, ld = threadIdx.x & 63;
  int row = blockIdx.x * 4 + w;
  const float4* xr = (const float4*)(x + (size_t)row * 256);
  float4 v = xr[ld];
  float s = v.x + v.y + v.z + v.w;
  float ss = v.x * v.x + v.y * v.y + v.z * v.z + v.w * v.w;
  #pragma unroll
  for (int off = 1; off < 64; off <<= 1) {
    s += __shfl_xor(s, off);
    ss += __shfl_xor(ss, off);
  }
  float mu = s * (1.0f / 256.0f);
  float var = ss * (1.0f / 256.0f) - mu * mu;
  float rstd = rsqrtf(var + EPS_);
  float4 g = ((const float4*)gamma)[ld];
  float4 bt = ((const float4*)beta)[ld];
  float4 o;
  o.x = (v.x - mu) * rstd * g.x + bt.x;
  o.y = (v.y - mu) * rstd * g.y + bt.y;
  o.z = (v.z - mu) * rstd * g.z + bt.z;
  o.w = (v.w - mu) * rstd * g.w + bt.w;
  ((float4*)(xn + (size_t)row * 256))[ld] = o;
}

// ---------------- fp32 tiled GEMM: C[m][n] = sum_k A[m*K+k] * Bm[n*K+k] ----------------
template <bool PROJ>
__global__ __launch_bounds__(256) void gemm_nt(const float* __restrict__ A,
                                               const float* __restrict__ Bm,
                                               float* __restrict__ C,
                                               const float* __restrict__ vres,
                                               const float* __restrict__ bias,
                                               int K, int ldc) {
  __shared__ float As[32][64];
  __shared__ float Bs[32][64];
  int m0 = blockIdx.x * 64, n0 = blockIdx.y * 64;
  int t = threadIdx.x;
  int tm = t & 15, tn = t >> 4;
  float acc[4][4] = {};
  for (int k0 = 0; k0 < K; k0 += 32) {
    __syncthreads();
    for (int f = t; f < 512; f += 256) {
      int row = f >> 3, j = f & 7;
      float4 a = *(const float4*)(A + (size_t)(m0 + row) * K + k0 + j * 4);
      As[j * 4 + 0][row] = a.x; As[j * 4 + 1][row] = a.y;
      As[j * 4 + 2][row] = a.z; As[j * 4 + 3][row] = a.w;
      float4 b = *(const float4*)(Bm + (size_t)(n0 + row) * K + k0 + j * 4);
      Bs[j * 4 + 0][row] = b.x; Bs[j * 4 + 1][row] = b.y;
      Bs[j * 4 + 2][row] = b.z; Bs[j * 4 + 3][row] = b.w;
    }
    __syncthreads();
    #pragma unroll
    for (int k = 0; k < 32; k++) {
      float4 a = *(const float4*)&As[k][tm * 4];
      float4 b = *(const float4*)&Bs[k][tn * 4];
      float av[4] = {a.x, a.y, a.z, a.w};
      float bv[4] = {b.x, b.y, b.z, b.w};
      #pragma unroll
      for (int i = 0; i < 4; i++)
        #pragma unroll
        for (int j = 0; j < 4; j++)
          acc[i][j] = fmaf(av[i], bv[j], acc[i][j]);
    }
  }
  #pragma unroll
  for (int i = 0; i < 4; i++) {
    int m = m0 + tm * 4 + i;
    int n = n0 + tn * 4;
    float4 r = {acc[i][0], acc[i][1], acc[i][2], acc[i][3]};
    if (PROJ) {
      float4 vr = *(const float4*)(vres + (size_t)m * 768 + n);
      float4 bb = *(const float4*)(bias + n);
      r.x += vr.x + bb.x; r.y += vr.y + bb.y;
      r.z += vr.z + bb.z; r.w += vr.w + bb.w;
    }
    *(float4*)(C + (size_t)m * ldc + n) = r;
  }
}

// ---------------- Flash attention v3: lane=row, K/V via wave-uniform scalar loads ----
// Block: 512 threads (8 waves) handles 64 query rows for one (b,h).
// Wave w owns s-columns w*8..w*8+7 of each 64-wide KV tile; lane (0..63) = query row.
// K/V addresses are wave-uniform (readfirstlane'd wid) -> compiler emits s_load into
// SGPRs; FMAs consume them as the scalar operand. NO LDS, NO barriers in main loop.
// This kills both the register spill (no staging regs) and the 64x LDS-broadcast
// return-bandwidth waste of the previous version.

__global__ __launch_bounds__(512, 2) void attn_kernel(const float* __restrict__ qkv,
                                                      float* __restrict__ msg,
                                                      float* __restrict__ out_s,
                                                      float* __restrict__ out_i) {
  const int l0 = blockIdx.x * 64;
  const int h = blockIdx.y;
  const int b = blockIdx.z;
  const int t = threadIdx.x;
  const int wid = __builtin_amdgcn_readfirstlane(t >> 6);  // wave-uniform -> SGPR
  const int lane = t & 63;
  const int c0 = wid * 8;  // this wave's column offset within a tile (uniform)

  __shared__ float Pm[8][64];
  __shared__ float Pl[8][64];
  __shared__ float Ptv[8][64][5];
  __shared__ int   Pti[8][64][5];
  __shared__ float AccO[64][33];  // padded: atomics conflict-free across lanes
  __shared__ float Fsc[64][4];
  __shared__ int   Ffi[64][4];
  __shared__ float Flinv[64];

  // ---- load this lane's q row (temp-scaled), per-lane vector loads ----
  const float* qrow = qkv + ((size_t)(b * N_) + l0 + lane) * 768 + h * DH_;
  float4 q[8];
  #pragma unroll
  for (int j = 0; j < 8; j++) {
    float4 v = ((const float4*)qrow)[j];
    v.x *= TEMP_; v.y *= TEMP_; v.z *= TEMP_; v.w *= TEMP_;
    q[j] = v;
  }

  float4 o[8];
  #pragma unroll
  for (int j = 0; j < 8; j++) o[j] = make_float4(0.f, 0.f, 0.f, 0.f);
  float m = -INFINITY, l = 0.f;
  float tv[4];
  int ti[4];
  #pragma unroll
  for (int i = 0; i < 4; i++) { tv[i] = -INFINITY; ti[i] = 0x7fffffff; }

  // Wave-uniform K/V base pointers (everything below depends only on uniforms).
  const float* Kg = qkv + (size_t)(b * N_) * 768 + 256 + h * DH_;
  const float* Vg = Kg + 256;

  #pragma unroll 1  // keep the tile loop rolled: full unroll would blow I$
  for (int t0 = 0; t0 < N_ / 64; ++t0) {
    const int s0 = t0 * 64;
    const float* kb = Kg + (size_t)(s0 + c0) * 768;

    // ---- QK: 8 columns, K chunks via uniform (scalar) loads ----
    float sv[8];
    #pragma unroll
    for (int c = 0; c < 8; ++c) {
      const float* kc = kb + (size_t)c * 768;
      float4 a = {0.f, 0.f, 0.f, 0.f};
      #pragma unroll
      for (int d = 0; d < 8; ++d) {
        float4 kv = *(const float4*)(kc + d * 4);  // uniform addr -> s_load
        float4 qv = q[d];
        a.x = fmaf(qv.x, kv.x, a.x);
        a.y = fmaf(qv.y, kv.y, a.y);
        a.z = fmaf(qv.z, kv.z, a.z);
        a.w = fmaf(qv.w, kv.w, a.w);
      }
      sv[c] = (a.x + a.y) + (a.z + a.w);
    }

    // ---- top-4 update (compile-time-indexed cascade: no scratch) ----
    #pragma unroll
    for (int i = 0; i < 8; ++i) {
      float sval = sv[i];
      int idx = s0 + c0 + i;
      if (sval > tv[3] || (sval == tv[3] && idx < ti[3])) {
        bool i2 = (sval > tv[2]) || (sval == tv[2] && idx < ti[2]);
        bool i1 = (sval > tv[1]) || (sval == tv[1] && idx < ti[1]);
        bool i0 = (sval > tv[0]) || (sval == tv[0] && idx < ti[0]);
        tv[3] = i2 ? tv[2] : sval; ti[3] = i2 ? ti[2] : idx;
        float nv2 = i1 ? tv[1] : sval; int ni2 = i1 ? ti[1] : idx;
        float nv1 = i0 ? tv[0] : sval; int ni1 = i0 ? ti[0] : idx;
        if (i2) { tv[2] = nv2; ti[2] = ni2; }
        if (i1) { tv[1] = nv1; ti[1] = ni1; }
        if (i0) { tv[0] = sval; ti[0] = idx; }
      }
    }

    // ---- online softmax (fully per-lane); p[] overwrites sv[] in place ----
    float tmax = fmaxf(fmaxf(fmaxf(sv[0], sv[1]), fmaxf(sv[2], sv[3])),
                       fmaxf(fmaxf(sv[4], sv[5]), fmaxf(sv[6], sv[7])));
    float mnew = fmaxf(m, tmax);
    float alpha = __expf(m - mnew);
    float ps = 0.f;
    #pragma unroll
    for (int i = 0; i < 8; ++i) { sv[i] = __expf(sv[i] - mnew); ps += sv[i]; }
    l = l * alpha + ps;
    m = mnew;
    #pragma unroll
    for (int ch = 0; ch < 8; ++ch) {
      o[ch].x *= alpha; o[ch].y *= alpha; o[ch].z *= alpha; o[ch].w *= alpha;
    }

    // ---- PV: V chunks via uniform (scalar) loads, p per-lane ----
    #pragma unroll
    for (int c = 0; c < 8; ++c) {
      float pc = sv[c];
      const float* vc = Vg + (size_t)(s0 + c0 + c) * 768;
      #pragma unroll
      for (int ch = 0; ch < 8; ++ch) {
        float4 vv = *(const float4*)(vc + ch * 4);  // uniform addr -> s_load
        o[ch].x = fmaf(pc, vv.x, o[ch].x);
        o[ch].y = fmaf(pc, vv.y, o[ch].y);
        o[ch].z = fmaf(pc, vv.z, o[ch].z);
        o[ch].w = fmaf(pc, vv.w, o[ch].w);
      }
    }
  }

  // ---- merge the 8 per-wave column-slice partials ----
  Pm[wid][lane] = m;
  Pl[wid][lane] = l;
  #pragma unroll
  for (int i = 0; i < 4; ++i) { Ptv[wid][lane][i] = tv[i]; Pti[wid][lane][i] = ti[i]; }
  for (int i = t; i < 64 * 33; i += 512) (&AccO[0][0])[i] = 0.f;
  __syncthreads();

  float mg = Pm[0][lane];
  #pragma unroll
  for (int j = 1; j < 8; ++j) mg = fmaxf(mg, Pm[j][lane]);
  float lg = 0.f;
  #pragma unroll
  for (int j = 0; j < 8; ++j) lg += Pl[j][lane] * __expf(Pm[j][lane] - mg);
  float aw = __expf(m - mg);
  #pragma unroll
  for (int ch = 0; ch < 8; ++ch) {
    atomicAdd(&AccO[lane][ch * 4 + 0], o[ch].x * aw);
    atomicAdd(&AccO[lane][ch * 4 + 1], o[ch].y * aw);
    atomicAdd(&AccO[lane][ch * 4 + 2], o[ch].z * aw);
    atomicAdd(&AccO[lane][ch * 4 + 3], o[ch].w * aw);
  }
  __syncthreads();

  if (wid == 0) {
    float linv = 1.f / lg;
    Flinv[lane] = linv;
    float fv[4];
    int fi[4];
    #pragma unroll
    for (int r = 0; r < 4; ++r) {
      float best = -INFINITY;
      int bi = 0x7fffffff, bj = 0, bii = 0;
      #pragma unroll
      for (int j = 0; j < 8; ++j)
        #pragma unroll
        for (int i2 = 0; i2 < 4; ++i2) {
          float v2 = Ptv[j][lane][i2];
          int ix = Pti[j][lane][i2];
          if (v2 > best || (v2 == best && ix < bi)) { best = v2; bi = ix; bj = j; bii = i2; }
        }
      Ptv[bj][lane][bii] = -INFINITY;  // LDS-indexed mark, stays off scratch
      fv[r] = best;
      fi[r] = bi;
    }
    size_t base = ((size_t)(b * N_) + l0 + lane) * TOPK_;
    #pragma unroll
    for (int r = 0; r < 4; ++r) {
      float sc = __expf(fv[r] - mg) * linv;
      Fsc[lane][r] = sc;
      Ffi[lane][r] = fi[r];
      out_s[(base + r) * H_ + h] = sc;
      out_i[(base + r) * H_ + h] = (float)fi[r];
    }
  }
  __syncthreads();

  // ---- final: normalize, subtract top-4 contributions, coalesced write ----
  {
    int r = t >> 3, dc = t & 7;
    float linv = Flinv[r];
    float ax = AccO[r][dc * 4 + 0] * linv;
    float ay = AccO[r][dc * 4 + 1] * linv;
    float az = AccO[r][dc * 4 + 2] * linv;
    float aw2 = AccO[r][dc * 4 + 3] * linv;
    #pragma unroll
    for (int k = 0; k < 4; ++k) {
      int idx = Ffi[r][k];
      float sc = Fsc[r][k];
      const float* vp = qkv + ((size_t)(b * N_) + idx) * 768 + 512 + h * DH_ + dc * 4;
      float4 vv = *(const float4*)vp;
      ax = fmaf(-sc, vv.x, ax); ay = fmaf(-sc, vv.y, ay);
      az = fmaf(-sc, vv.z, az); aw2 = fmaf(-sc, vv.w, aw2);
    }
    float4 r4 = {ax, ay, az, aw2};
    *(float4*)(msg + ((size_t)(b * N_) + l0 + r) * DIM_ + h * DH_ + dc * 4) = r4;
  }
}

extern "C" void kernel_launch(void* const* d_in, const int* in_sizes, int n_in,
                              void* d_out, int out_size, void* d_ws, size_t ws_size,
                              hipStream_t stream) {
  const float* points = (const float*)d_in[0];
  const float* norm_gamma = (const float*)d_in[1];
  const float* norm_beta = (const float*)d_in[2];
  const float* w_qkv = (const float*)d_in[3];
  const float* w_proj = (const float*)d_in[4];
  const float* b_proj = (const float*)d_in[5];

  float* out0 = (float*)d_out;                       // message_flat (4096*256)
  float* out1 = out0 + (size_t)4096 * 256;           // topk_score (4096*4*8)
  float* out2 = out1 + (size_t)4096 * 4 * 8;         // topk_idx as float

  float* xn = (float*)d_ws;                          // 4096*256
  float* qkv = xn + (size_t)4096 * 256;              // 4096*768
  float* msg = qkv + (size_t)4096 * 768;             // 4096*256

  ln_kernel<<<1024, 256, 0, stream>>>(points, norm_gamma, norm_beta, xn);
  gemm_nt<false><<<dim3(64, 12), 256, 0, stream>>>(xn, w_qkv, qkv, nullptr,
                                                   nullptr, 256, 768);
  attn_kernel<<<dim3(N_ / 64, H_, B_), 512, 0, stream>>>(qkv, msg, out1, out2);
  gemm_nt<true><<<dim3(64, 4), 256, 0, stream>>>(msg, w_proj, out0, qkv + 512,
                                                 b_proj, 256, 256);
}